// Round 12
// baseline (156.601 us; speedup 1.0000x reference)
//
#include <hip/hip_runtime.h>
#include <math.h>

#define BB 2
#define II 128
#define JJ 512
#define CC 256
#define NEL (BB*II*JJ)   // 131072
#define NINF (-INFINITY)
#define K10 4.5399929762484854e-5f   // exp(-10)

typedef float f32x4 __attribute__((ext_vector_type(4)));   // asm-operand-safe vec4

// ---------------- DPP wave64 primitives ----------------
template<int CTRL, int RM = 0xf, int BM = 0xf, bool BC = true>
__device__ __forceinline__ float dppf(float x) {
    return __int_as_float(__builtin_amdgcn_update_dpp(
        0, __float_as_int(x), CTRL, RM, BM, BC));
}
template<int CTRL, int RM = 0xf, int BM = 0xf>
__device__ __forceinline__ float dppself(float x) {
    return __int_as_float(__builtin_amdgcn_update_dpp(
        __float_as_int(x), __float_as_int(x), CTRL, RM, BM, false));
}
__device__ __forceinline__ float wscan_incl(float x) {
    x += dppf<0x111>(x);
    x += dppf<0x112>(x);
    x += dppf<0x114>(x);
    x += dppf<0x118>(x);
    x += dppf<0x142, 0xa>(x);
    x += dppf<0x143, 0xc>(x);
    return x;
}
__device__ __forceinline__ float wscan_maxf(float x) {
    x = fmaxf(x, dppself<0x111>(x));
    x = fmaxf(x, dppself<0x112>(x));
    x = fmaxf(x, dppself<0x114>(x));
    x = fmaxf(x, dppself<0x118>(x));
    x = fmaxf(x, dppself<0x142, 0xa>(x));
    x = fmaxf(x, dppself<0x143, 0xc>(x));
    return x;
}
__device__ __forceinline__ float lane_shr1(float x) { return dppf<0x138>(x); }
__device__ __forceinline__ float bcast63(float x) {
    return __int_as_float(__builtin_amdgcn_readlane(__float_as_int(x), 63));
}

__device__ __forceinline__ void tree_prefix8(const float x[8], float P[8]) {
    float t[8];
    t[0] = x[0];
    #pragma unroll
    for (int q = 1; q < 8; ++q) t[q] = x[q] + x[q-1];
    float u[8];
    u[0] = t[0]; u[1] = t[1];
    #pragma unroll
    for (int q = 2; q < 8; ++q) u[q] = t[q] + t[q-2];
    P[0] = u[0]; P[1] = u[1]; P[2] = u[2]; P[3] = u[3];
    #pragma unroll
    for (int q = 4; q < 8; ++q) P[q] = u[q] + u[q-4];
}

__device__ __forceinline__ void loadrow8(const float* p, float v[8]) {
    float4 a = *reinterpret_cast<const float4*>(p);
    float4 b = *reinterpret_cast<const float4*>(p + 4);
    v[0]=a.x; v[1]=a.y; v[2]=a.z; v[3]=a.w;
    v[4]=b.x; v[5]=b.y; v[6]=b.z; v[7]=b.w;
}
__device__ __forceinline__ void storerow8(float* __restrict__ p, const float v[8]) {
    *reinterpret_cast<float4*>(p)     = make_float4(v[0],v[1],v[2],v[3]);
    *reinterpret_cast<float4*>(p + 4) = make_float4(v[4],v[5],v[6],v[7]);
}

// ---------------- hand-held vmem ops (invisible to SIInsertWaitcnts) ----------------
__device__ __forceinline__ void aload2(f32x4 &d0, f32x4 &d1, const float* p) {
    asm volatile("global_load_dwordx4 %0, %2, off\n\t"
                 "global_load_dwordx4 %1, %2, off offset:16"
                 : "=&v"(d0), "=&v"(d1) : "v"(p) : "memory");
}
__device__ __forceinline__ void astore2(f32x4 d0, f32x4 d1, float* p) {
    asm volatile("global_store_dwordx4 %2, %0, off\n\t"
                 "global_store_dwordx4 %2, %1, off offset:16"
                 :: "v"(d0), "v"(d1), "v"(p) : "memory");
}
template<int N> __device__ __forceinline__ void waitcnt_vm() {
    asm volatile("s_waitcnt vmcnt(%0)" :: "i"(N) : "memory");
}

struct Buf { f32x4 e0, e1; };   // one e-row fragment: 8 VGPRs

// fused dscan: CE = exp(ev - rowmax); CW = 1/(inclusive suffix sum of CE)
__device__ __forceinline__ void preproc(const float ev[8], float CE[8], float CW[8]) {
    float m8 = fmaxf(fmaxf(fmaxf(ev[0],ev[1]), fmaxf(ev[2],ev[3])),
                     fmaxf(fmaxf(ev[4],ev[5]), fmaxf(ev[6],ev[7])));
    float m = bcast63(wscan_maxf(m8));
    float x[8];
    #pragma unroll
    for (int q = 0; q < 8; ++q) x[q] = __expf(ev[q] - m);
    float P[8];
    tree_prefix8(x, P);
    float sc = wscan_incl(P[7]);
    float cp = lane_shr1(sc);
    float T  = bcast63(sc);
    #pragma unroll
    for (int q = 0; q < 8; ++q) {
        CE[q] = x[q];
        CW[q] = __builtin_amdgcn_rcpf(T - (cp + P[q]) + x[q]);
    }
}

// ---------------- energy: tiled outer-product GEMM ----------------
__global__ __launch_bounds__(256) void energy_kernel(
        const float* __restrict__ text, const float* __restrict__ mel,
        const float* __restrict__ noise, const float* __restrict__ ratio,
        float* __restrict__ e) {
    __shared__ float melS[64][65];
    __shared__ float texS[8][65];
    int b  = blockIdx.x;
    int i0 = blockIdx.y * 8;
    int j0 = blockIdx.z * 64;
    int t = threadIdx.x;
    int jj = t & 63, ig = t >> 6;
    float acc0 = 0.f, acc1 = 0.f;
    for (int cc = 0; cc < CC; cc += 64) {
        #pragma unroll
        for (int k = 0; k < 4; ++k) {
            int idx = t + k * 256;
            int row = idx >> 4, seg = idx & 15;
            float4 v = *reinterpret_cast<const float4*>(
                mel + (size_t)(b * JJ + j0 + row) * CC + cc + seg * 4);
            melS[row][seg*4+0] = v.x; melS[row][seg*4+1] = v.y;
            melS[row][seg*4+2] = v.z; melS[row][seg*4+3] = v.w;
        }
        if (t < 128) {
            int row = t >> 4, seg = t & 15;
            float4 v = *reinterpret_cast<const float4*>(
                text + (size_t)(b * II + i0 + row) * CC + cc + seg * 4);
            texS[row][seg*4+0] = v.x; texS[row][seg*4+1] = v.y;
            texS[row][seg*4+2] = v.z; texS[row][seg*4+3] = v.w;
        }
        __syncthreads();
        #pragma unroll 8
        for (int c = 0; c < 64; ++c) {
            float m = melS[jj][c];
            acc0 = fmaf(m, texS[ig*2+0][c], acc0);
            acc1 = fmaf(m, texS[ig*2+1][c], acc1);
        }
        __syncthreads();
    }
    float temp = 0.1f + 0.9f * ratio[0];
    float rtmp = 1.0f / temp;
    int r0 = (b * II + i0 + ig*2 + 0) * JJ + j0 + jj;
    int r1 = (b * II + i0 + ig*2 + 1) * JJ + j0 + jj;
    e[r0] = (acc0 * (1.0f/256.0f) + noise[r0]) * rtmp;
    e[r1] = (acc1 * (1.0f/256.0f) + noise[r1]) * rtmp;
}

// ======================= scan_ab: fused dscan, preproc pipelined 1 ahead, d=7 =======================
// R11 lesson: preproc(row i) feeding p-chain(i) directly = strictly serial chain,
// dep stalls fully exposed (1400cy/step). Here preproc(row i+1) runs during step i:
// independent of p-chain(i) (which uses CE/CW from step i-1's preproc) -> the
// compiler's list scheduler interleaves the two chains in the region after the
// wait, filling each chain's dependency stalls with the other's instructions.
// d=7 (4 vmem ops/step, peak in-flight 28 < 32-cap): store-ack age 7 steps.
// Per step order: [2 stores][wait VM][ev extract][2 loads row i+-8][preproc(next)
// || p-chain(cur)]. Ledger: warm 4/8/12/16/20/24 (exact no-ops), steady 26,
// tail 26/24/22/20/18/16/14/skip. Buf ring 7 in-place; P ring 14 (store-source
// regs rewritten 13 steps later, retired by steady wait); CE/CW ping-pong A/B;
// NORM cadence 7. ca/cb in LDS (lgkm domain, not in vmcnt stream).

template<bool NORM, int VM, bool PF, bool PP>
__device__ __forceinline__ void astep(
    int i, int lane, int off,
    const float (&pin)[8], float (&pout)[8], float& c,
    Buf& B,
    const float (&CEc)[8], const float (&CWc)[8],
    float (&CEn)[8], float (&CWn)[8],
    const float* __restrict__ eB,
    float* __restrict__ paB, float* ldsC)
{
    {
        f32x4 s0 = {pin[0], pin[1], pin[2], pin[3]};
        f32x4 s1 = {pin[4], pin[5], pin[6], pin[7]};
        astore2(s0, s1, paB + (size_t)(i - 1) * JJ + off);   // pin holds row i-1
    }
    if (lane == 0) ldsC[i - 1] = c;
    if constexpr (VM >= 0) {
        waitcnt_vm<VM>();
        __builtin_amdgcn_sched_barrier(0);   // rule #18
    }
    float ev[8];
    if (PP) {
        ev[0]=B.e0[0]; ev[1]=B.e0[1]; ev[2]=B.e0[2]; ev[3]=B.e0[3];
        ev[4]=B.e1[0]; ev[5]=B.e1[1]; ev[6]=B.e1[2]; ev[7]=B.e1[3];
    }
    if (PF) aload2(B.e0, B.e1, eB + (size_t)(i + 8) * JJ + off);  // reload slot with row i+8
    if (PP) preproc(ev, CEn, CWn);           // independent of p-chain below -> interleaved

    float pup = lane_shr1(pin[7]);
    float y[8];
    y[0] = pup * CWc[0];
    #pragma unroll
    for (int q = 1; q < 8; ++q) y[q] = pin[q-1] * CWc[q];
    float zz[8];
    #pragma unroll
    for (int q = 0; q < 7; ++q) zz[q] = pin[q];
    zz[7] = (lane == 63) ? 0.0f : pin[7];
    float Y[8], Z[8];
    tree_prefix8(y, Y);
    tree_prefix8(zz, Z);
    float sy = wscan_incl(Y[7]);
    float sz = wscan_incl(Z[7]);
    float oy = lane_shr1(sy);
    float oz = lane_shr1(sz);
    float T  = bcast63(sz);
    #pragma unroll
    for (int q = 0; q < 8; ++q) {
        float S1 = oy + Y[q];
        float S2 = fmaxf(T - (oz + Z[q]) + zz[q], 0.0f);
        pout[q] = fmaf(CEc[q], S1, K10 * S2);
    }
    if (NORM) {
        float Tc = fmaxf(T, 1e-30f);
        float rT = __builtin_amdgcn_rcpf(Tc);
        c += __logf(Tc);
        #pragma unroll
        for (int q = 0; q < 8; ++q) pout[q] *= rT;
    }
}

template<bool NORM, int VM, bool PF, bool PP>
__device__ __forceinline__ void bstep(
    int i, int lane, int off,
    const float (&pin)[8], float (&pout)[8], float& c,
    Buf& B,
    const float (&CEc)[8], const float (&CWc)[8],
    float (&CEn)[8], float (&CWn)[8],
    const float* __restrict__ eB,
    float* __restrict__ pbB, float* ldsC)
{
    {
        f32x4 s0 = {pin[0], pin[1], pin[2], pin[3]};
        f32x4 s1 = {pin[4], pin[5], pin[6], pin[7]};
        astore2(s0, s1, pbB + (size_t)(i + 1) * JJ + off);   // pin holds row i+1
    }
    if (lane == 0) ldsC[i + 1] = c;
    if constexpr (VM >= 0) {
        waitcnt_vm<VM>();
        __builtin_amdgcn_sched_barrier(0);
    }
    float ev[8];
    if (PP) {   // reversed: ev[q] = row[511 - 8*lane - q]
        ev[0]=B.e1[3]; ev[1]=B.e1[2]; ev[2]=B.e1[1]; ev[3]=B.e1[0];
        ev[4]=B.e0[3]; ev[5]=B.e0[2]; ev[6]=B.e0[1]; ev[7]=B.e0[0];
    }
    if (PF) aload2(B.e0, B.e1, eB + (size_t)(i - 8) * JJ + 504 - 8 * lane);
    if (PP) preproc(ev, CEn, CWn);

    float pup = lane_shr1(pin[7]);
    float pn[8];
    pn[0] = pup;
    #pragma unroll
    for (int q = 1; q < 8; ++q) pn[q] = pin[q-1];
    float w[8];
    #pragma unroll
    for (int q = 0; q < 8; ++q) w[q] = pn[q] * CWc[q];
    float W[8], N[8];
    tree_prefix8(w, W);
    tree_prefix8(pn, N);
    float sw = wscan_incl(W[7]);
    float sn = wscan_incl(N[7]);
    float ow = lane_shr1(sw);
    float on = lane_shr1(sn);
    float T  = bcast63(sn);
    #pragma unroll
    for (int q = 0; q < 8; ++q) {
        float QA = ow + W[q];
        float QB = fmaxf(T - (on + N[q]), 0.0f);
        pout[q] = fmaf(CEc[q], QA, K10 * QB);
    }
    if (NORM) {
        float Tc = fmaxf(T, 1e-30f);
        float rT = __builtin_amdgcn_rcpf(Tc);
        c += __logf(Tc);
        #pragma unroll
        for (int q = 0; q < 8; ++q) pout[q] *= rT;
    }
}

__global__ __launch_bounds__(64, 1) void scan_ab_kernel(
        const float* __restrict__ e,
        float* __restrict__ pa, float* __restrict__ pb,
        float* __restrict__ ca, float* __restrict__ cb) {
    __shared__ float ldsC[II];
    int b = blockIdx.x >> 1, dir = blockIdx.x & 1;
    int lane = threadIdx.x, off = lane * 8;
    size_t base = (size_t)b * II * JJ;
    float PS0[8],PS1[8],PS2[8],PS3[8],PS4[8],PS5[8],PS6[8],PS7[8],
          PS8[8],PS9[8],PS10[8],PS11[8],PS12[8],PS13[8];
    Buf B0,B1,B2,B3,B4,B5,B6;    // slot = row % 7
    float CEa[8], CWa[8], CEb[8], CWb[8];   // ping-pong: CI=0 consumes A/produces B
    float c = 0.0f;

    if (dir == 0) {
        const float* eB = e + base;
        float* paB = pa + base; float* caB = ca + b * II;
        // row 0 via compiler loads: PS0 = exp(e0-m)/rowsum
        float e0r[8];
        loadrow8(eB + off, e0r);
        {
            float m8 = fmaxf(fmaxf(fmaxf(e0r[0],e0r[1]), fmaxf(e0r[2],e0r[3])),
                             fmaxf(fmaxf(e0r[4],e0r[5]), fmaxf(e0r[6],e0r[7])));
            float m = bcast63(wscan_maxf(m8));
            float x0[8];
            #pragma unroll
            for (int q = 0; q < 8; ++q) x0[q] = __expf(e0r[q] - m);
            float P[8];
            tree_prefix8(x0, P);
            float T = bcast63(wscan_incl(P[7]));
            float rT = __builtin_amdgcn_rcpf(T);
            #pragma unroll
            for (int q = 0; q < 8; ++q) PS0[q] = x0[q] * rT;
        }
        __builtin_amdgcn_sched_barrier(0);
        // asm prefetch rows 1..7 -> slots 1..6,0 (14 ops)
        aload2(B1.e0, B1.e1, eB + (size_t)1*JJ + off);
        aload2(B2.e0, B2.e1, eB + (size_t)2*JJ + off);
        aload2(B3.e0, B3.e1, eB + (size_t)3*JJ + off);
        aload2(B4.e0, B4.e1, eB + (size_t)4*JJ + off);
        aload2(B5.e0, B5.e1, eB + (size_t)5*JJ + off);
        aload2(B6.e0, B6.e1, eB + (size_t)6*JJ + off);
        aload2(B0.e0, B0.e1, eB + (size_t)7*JJ + off);
        waitcnt_vm<0>();
        __builtin_amdgcn_sched_barrier(0);
        {   // prologue preproc(row 1) -> buf B (consumed by step 1, CI=1); reload slot1 with row 8
            float ev[8] = {B1.e0[0],B1.e0[1],B1.e0[2],B1.e0[3],B1.e1[0],B1.e1[1],B1.e1[2],B1.e1[3]};
            aload2(B1.e0, B1.e1, eB + (size_t)8*JJ + off);
            preproc(ev, CEb, CWb);
        }
        // warm-up steps 1..6 (VM = exact no-ops), step 7 = first real wait
        astep<true , 4,true,true>(1, lane, off, PS0, PS1, c, B2, CEb,CWb, CEa,CWa, eB, paB, ldsC);
        astep<false, 8,true,true>(2, lane, off, PS1, PS2, c, B3, CEa,CWa, CEb,CWb, eB, paB, ldsC);
        astep<false,12,true,true>(3, lane, off, PS2, PS3, c, B4, CEb,CWb, CEa,CWa, eB, paB, ldsC);
        astep<false,16,true,true>(4, lane, off, PS3, PS4, c, B5, CEa,CWa, CEb,CWb, eB, paB, ldsC);
        astep<false,20,true,true>(5, lane, off, PS4, PS5, c, B6, CEb,CWb, CEa,CWa, eB, paB, ldsC);
        astep<false,24,true,true>(6, lane, off, PS5, PS6, c, B0, CEa,CWa, CEb,CWb, eB, paB, ldsC);
        astep<false,26,true,true>(7, lane, off, PS6, PS7, c, B1, CEb,CWb, CEa,CWa, eB, paB, ldsC);
        #pragma unroll 1
        for (int d = 0; d < 8; ++d) {        // steps 8..119 = 8 x 14
            int i = 8 + 14 * d;
            astep<true ,26,true,true>(i+ 0, lane, off, PS7 , PS8 , c, B2, CEa,CWa, CEb,CWb, eB, paB, ldsC);
            astep<false,26,true,true>(i+ 1, lane, off, PS8 , PS9 , c, B3, CEb,CWb, CEa,CWa, eB, paB, ldsC);
            astep<false,26,true,true>(i+ 2, lane, off, PS9 , PS10, c, B4, CEa,CWa, CEb,CWb, eB, paB, ldsC);
            astep<false,26,true,true>(i+ 3, lane, off, PS10, PS11, c, B5, CEb,CWb, CEa,CWa, eB, paB, ldsC);
            astep<false,26,true,true>(i+ 4, lane, off, PS11, PS12, c, B6, CEa,CWa, CEb,CWb, eB, paB, ldsC);
            astep<false,26,true,true>(i+ 5, lane, off, PS12, PS13, c, B0, CEb,CWb, CEa,CWa, eB, paB, ldsC);
            astep<false,26,true,true>(i+ 6, lane, off, PS13, PS0 , c, B1, CEa,CWa, CEb,CWb, eB, paB, ldsC);
            astep<true ,26,true,true>(i+ 7, lane, off, PS0 , PS1 , c, B2, CEb,CWb, CEa,CWa, eB, paB, ldsC);
            astep<false,26,true,true>(i+ 8, lane, off, PS1 , PS2 , c, B3, CEa,CWa, CEb,CWb, eB, paB, ldsC);
            astep<false,26,true,true>(i+ 9, lane, off, PS2 , PS3 , c, B4, CEb,CWb, CEa,CWa, eB, paB, ldsC);
            astep<false,26,true,true>(i+10, lane, off, PS3 , PS4 , c, B5, CEa,CWa, CEb,CWb, eB, paB, ldsC);
            astep<false,26,true,true>(i+11, lane, off, PS4 , PS5 , c, B6, CEb,CWb, CEa,CWa, eB, paB, ldsC);
            astep<false,26,true,true>(i+12, lane, off, PS5 , PS6 , c, B0, CEa,CWa, CEb,CWb, eB, paB, ldsC);
            astep<false,26,true,true>(i+13, lane, off, PS6 , PS7 , c, B1, CEb,CWb, CEa,CWa, eB, paB, ldsC);
        }
        // tail 120..127 (no PF; preproc continues through 126)
        astep<true ,26,false,true >(120, lane, off, PS7 , PS8 , c, B2, CEa,CWa, CEb,CWb, eB, paB, ldsC);
        astep<false,24,false,true >(121, lane, off, PS8 , PS9 , c, B3, CEb,CWb, CEa,CWa, eB, paB, ldsC);
        astep<false,22,false,true >(122, lane, off, PS9 , PS10, c, B4, CEa,CWa, CEb,CWb, eB, paB, ldsC);
        astep<false,20,false,true >(123, lane, off, PS10, PS11, c, B5, CEb,CWb, CEa,CWa, eB, paB, ldsC);
        astep<false,18,false,true >(124, lane, off, PS11, PS12, c, B6, CEa,CWa, CEb,CWb, eB, paB, ldsC);
        astep<false,16,false,true >(125, lane, off, PS12, PS13, c, B0, CEb,CWb, CEa,CWa, eB, paB, ldsC);
        astep<false,14,false,true >(126, lane, off, PS13, PS0 , c, B1, CEa,CWa, CEb,CWb, eB, paB, ldsC);
        astep<true ,-1,false,false>(127, lane, off, PS0 , PS1 , c, B2, CEb,CWb, CEa,CWa, eB, paB, ldsC);
        storerow8(paB + (size_t)127 * JJ + off, PS1);
        if (lane == 0) ldsC[127] = c;
        waitcnt_vm<0>();
        caB[lane]      = ldsC[lane];
        caB[lane + 64] = ldsC[lane + 64];
    } else {
        const float* eB = e + base;
        float* pbB = pb + base; float* cbB = cb + b * II;
        #pragma unroll
        for (int q = 0; q < 8; ++q) PS0[q] = 0.0f;
        PS0[0] = (lane == 0) ? 1.0f : 0.0f;   // row 127 (j'=0 <-> orig j=J-1)
        // asm prefetch rows 126..120 -> slots 0,6,5,4,3,2,1 (14 ops, reversed addressing)
        aload2(B0.e0, B0.e1, eB + (size_t)126*JJ + 504 - 8*lane);
        aload2(B6.e0, B6.e1, eB + (size_t)125*JJ + 504 - 8*lane);
        aload2(B5.e0, B5.e1, eB + (size_t)124*JJ + 504 - 8*lane);
        aload2(B4.e0, B4.e1, eB + (size_t)123*JJ + 504 - 8*lane);
        aload2(B3.e0, B3.e1, eB + (size_t)122*JJ + 504 - 8*lane);
        aload2(B2.e0, B2.e1, eB + (size_t)121*JJ + 504 - 8*lane);
        aload2(B1.e0, B1.e1, eB + (size_t)120*JJ + 504 - 8*lane);
        waitcnt_vm<0>();
        __builtin_amdgcn_sched_barrier(0);
        {   // prologue preproc(row 126) -> buf A (step 126, CI=0); reload slot0 with row 119
            float ev[8] = {B0.e1[3],B0.e1[2],B0.e1[1],B0.e1[0],B0.e0[3],B0.e0[2],B0.e0[1],B0.e0[0]};
            aload2(B0.e0, B0.e1, eB + (size_t)119*JJ + 504 - 8*lane);
            preproc(ev, CEa, CWa);
        }
        // warm-up steps 126..121 (VM no-ops), step 120 = first real wait
        bstep<true , 4,true,true>(126, lane, off, PS0, PS1, c, B6, CEa,CWa, CEb,CWb, eB, pbB, ldsC);
        bstep<false, 8,true,true>(125, lane, off, PS1, PS2, c, B5, CEb,CWb, CEa,CWa, eB, pbB, ldsC);
        bstep<false,12,true,true>(124, lane, off, PS2, PS3, c, B4, CEa,CWa, CEb,CWb, eB, pbB, ldsC);
        bstep<false,16,true,true>(123, lane, off, PS3, PS4, c, B3, CEb,CWb, CEa,CWa, eB, pbB, ldsC);
        bstep<false,20,true,true>(122, lane, off, PS4, PS5, c, B2, CEa,CWa, CEb,CWb, eB, pbB, ldsC);
        bstep<false,24,true,true>(121, lane, off, PS5, PS6, c, B1, CEb,CWb, CEa,CWa, eB, pbB, ldsC);
        bstep<false,26,true,true>(120, lane, off, PS6, PS7, c, B0, CEa,CWa, CEb,CWb, eB, pbB, ldsC);
        #pragma unroll 1
        for (int d = 0; d < 8; ++d) {        // steps 119..8 = 8 x 14
            int i = 119 - 14 * d;
            bstep<true ,26,true,true>(i- 0, lane, off, PS7 , PS8 , c, B6, CEb,CWb, CEa,CWa, eB, pbB, ldsC);
            bstep<false,26,true,true>(i- 1, lane, off, PS8 , PS9 , c, B5, CEa,CWa, CEb,CWb, eB, pbB, ldsC);
            bstep<false,26,true,true>(i- 2, lane, off, PS9 , PS10, c, B4, CEb,CWb, CEa,CWa, eB, pbB, ldsC);
            bstep<false,26,true,true>(i- 3, lane, off, PS10, PS11, c, B3, CEa,CWa, CEb,CWb, eB, pbB, ldsC);
            bstep<false,26,true,true>(i- 4, lane, off, PS11, PS12, c, B2, CEb,CWb, CEa,CWa, eB, pbB, ldsC);
            bstep<false,26,true,true>(i- 5, lane, off, PS12, PS13, c, B1, CEa,CWa, CEb,CWb, eB, pbB, ldsC);
            bstep<false,26,true,true>(i- 6, lane, off, PS13, PS0 , c, B0, CEb,CWb, CEa,CWa, eB, pbB, ldsC);
            bstep<true ,26,true,true>(i- 7, lane, off, PS0 , PS1 , c, B6, CEa,CWa, CEb,CWb, eB, pbB, ldsC);
            bstep<false,26,true,true>(i- 8, lane, off, PS1 , PS2 , c, B5, CEb,CWb, CEa,CWa, eB, pbB, ldsC);
            bstep<false,26,true,true>(i- 9, lane, off, PS2 , PS3 , c, B4, CEa,CWa, CEb,CWb, eB, pbB, ldsC);
            bstep<false,26,true,true>(i-10, lane, off, PS3 , PS4 , c, B3, CEb,CWb, CEa,CWa, eB, pbB, ldsC);
            bstep<false,26,true,true>(i-11, lane, off, PS4 , PS5 , c, B2, CEa,CWa, CEb,CWb, eB, pbB, ldsC);
            bstep<false,26,true,true>(i-12, lane, off, PS5 , PS6 , c, B1, CEb,CWb, CEa,CWa, eB, pbB, ldsC);
            bstep<false,26,true,true>(i-13, lane, off, PS6 , PS7 , c, B0, CEa,CWa, CEb,CWb, eB, pbB, ldsC);
        }
        // tail 7..0 (no PF; preproc continues through step 1)
        bstep<true ,26,false,true >(7, lane, off, PS7 , PS8 , c, B6, CEb,CWb, CEa,CWa, eB, pbB, ldsC);
        bstep<false,24,false,true >(6, lane, off, PS8 , PS9 , c, B5, CEa,CWa, CEb,CWb, eB, pbB, ldsC);
        bstep<false,22,false,true >(5, lane, off, PS9 , PS10, c, B4, CEb,CWb, CEa,CWa, eB, pbB, ldsC);
        bstep<false,20,false,true >(4, lane, off, PS10, PS11, c, B3, CEa,CWa, CEb,CWb, eB, pbB, ldsC);
        bstep<false,18,false,true >(3, lane, off, PS11, PS12, c, B2, CEb,CWb, CEa,CWa, eB, pbB, ldsC);
        bstep<false,16,false,true >(2, lane, off, PS12, PS13, c, B1, CEa,CWa, CEb,CWb, eB, pbB, ldsC);
        bstep<false,14,false,true >(1, lane, off, PS13, PS0 , c, B0, CEb,CWb, CEa,CWa, eB, pbB, ldsC);
        bstep<true ,-1,false,false>(0, lane, off, PS0 , PS1 , c, B6, CEa,CWa, CEb,CWb, eB, pbB, ldsC);
        storerow8(pbB + off, PS1);          // row 0
        if (lane == 0) ldsC[0] = c;
        waitcnt_vm<0>();
        cbB[lane]      = ldsC[lane];
        cbB[lane + 64] = ldsC[lane + 64];
    }
}

// ---------------- fused gamma + expand ----------------
__global__ __launch_bounds__(256) void gamma_expand_kernel(
        const float* __restrict__ pa, const float* __restrict__ pb,
        const float* __restrict__ ca, const float* __restrict__ cb,
        const float* __restrict__ text, const float* __restrict__ mmask,
        float* __restrict__ gamma_out, float* __restrict__ expanded) {
    __shared__ float wt[II][9];
    __shared__ float Ei[II];
    __shared__ float red[8][33];
    int b   = blockIdx.x >> 6;
    int jj0 = (blockIdx.x & 63) * 8;
    int t = threadIdx.x;
    int q = t & 7, ic = t >> 3;

    if (t < II) Ei[t] = ca[b*II + t] + cb[b*II + t];
    __syncthreads();
    float maxc = Ei[0];
    #pragma unroll 16
    for (int i = 1; i < II; ++i) maxc = fmaxf(maxc, Ei[i]);
    __syncthreads();
    if (t < II) Ei[t] = __expf(Ei[t] - maxc);
    __syncthreads();

    size_t idx0  = (size_t)b * II * JJ + jj0 + q;
    size_t idx0r = (size_t)b * II * JJ + (JJ - 1 - jj0 - q);   // pb stored j-reversed
    float d = 0.f;
    #pragma unroll
    for (int k = 0; k < 4; ++k) {
        int i = ic * 4 + k;
        float P = pa[idx0 + (size_t)i * JJ] * pb[idx0r + (size_t)i * JJ] * Ei[i];
        wt[i][q] = P;
        d += P;
    }
    red[q][ic] = d;
    __syncthreads();
    if (t < 8) {
        float s = 0.f;
        #pragma unroll
        for (int k = 0; k < 32; ++k) s += red[t][k];
        red[t][32] = 1.0f / fmaxf(s, 1e-37f);
    }
    __syncthreads();
    float rD = red[q][32];
    #pragma unroll
    for (int k = 0; k < 4; ++k) {
        int i = ic * 4 + k;
        float P = wt[i][q] * rD;
        wt[i][q] = P;
        gamma_out[idx0 + (size_t)i * JJ] = fmaxf(__logf(P), -1e30f);
    }
    __syncthreads();

    float acc[8] = {0,0,0,0,0,0,0,0};
    const float* txb = text + (size_t)b * II * CC + t;
    #pragma unroll 4
    for (int i = 0; i < II; ++i) {
        float tv = txb[(size_t)i * CC];
        #pragma unroll
        for (int qq = 0; qq < 8; ++qq) acc[qq] = fmaf(wt[i][qq], tv, acc[qq]);
    }
    #pragma unroll
    for (int qq = 0; qq < 8; ++qq) {
        expanded[(size_t)(b * JJ + jj0 + qq) * CC + t] =
            acc[qq] * mmask[b * JJ + jj0 + qq];
    }
}

extern "C" void kernel_launch(void* const* d_in, const int* in_sizes, int n_in,
                              void* d_out, int out_size, void* d_ws, size_t ws_size,
                              hipStream_t stream) {
    const float* text  = (const float*)d_in[0];
    const float* mel   = (const float*)d_in[1];
    const float* mmask = (const float*)d_in[3];
    const float* noise = (const float*)d_in[4];
    const float* ratio = (const float*)d_in[5];
    float* gamma_out = (float*)d_out;            // B*I*J floats
    float* expanded  = (float*)d_out + NEL;      // B*J*C floats

    float* ws = (float*)d_ws;
    float* e  = ws;                  // NEL
    float* pa = ws +   NEL;          // NEL
    float* pb = ws + 2*NEL;          // NEL (j-reversed layout)
    float* ca = ws + 3*NEL;          // BB*II
    float* cb = ws + 3*NEL + BB*II;  // BB*II

    hipLaunchKernelGGL(energy_kernel, dim3(BB, II/8, JJ/64), dim3(256), 0, stream,
                       text, mel, noise, ratio, e);
    hipLaunchKernelGGL(scan_ab_kernel, dim3(BB*2), dim3(64), 0, stream,
                       e, pa, pb, ca, cb);
    hipLaunchKernelGGL(gamma_expand_kernel, dim3(BB*64), dim3(256), 0, stream,
                       pa, pb, ca, cb, text, mmask, gamma_out, expanded);
}